// Round 13
// baseline (462.257 us; speedup 1.0000x reference)
//
#include <hip/hip_runtime.h>

// ---------------------------------------------------------------------------
// Batch-inner LeNet, LDS-staged MFMA conv2. lane = image, activations
// [feature][N]. conv2 = GEMM C[16oc][imgs] with K=150 staged per-ci into
// LDS (packed hi/lo bf16 dwords). hi/lo split: 3 MFMAs ~ fp32 precision
// (numerics proven in R12: absmax unchanged vs fp32). Verified layouts:
//   A[16x32]: row=lane&15 (oc), k=(lane>>4)*8+j
//   B[32x16]: col=lane&15 (img), k=(lane>>4)*8+j
//   D[16x16]: col=lane&15 (img), row=(lane>>4)*4+reg (oc)
// Block = 64 imgs x 1 quad-row-pair (20 conv pos); wave = 16-img group.
// acc[20] f32x4 lives in AGPRs (native MFMA accumulator - no parking cost).
// Pooling free in epilogue (all 4 sub-pos of a quad in-wave).
// ---------------------------------------------------------------------------

typedef __attribute__((ext_vector_type(8))) short bf16x8;
typedef __attribute__((ext_vector_type(4))) float f32x4;

union PackB { uint32_t u[4]; bf16x8 v; };

#define LSTRIDE 68              // row stride (dwords): 68%32=4 -> bank spread

__device__ __forceinline__ int xcd_swizzle(int orig, int nwg) {
    int xcd = orig & 7, q = nwg >> 3, r = nwg & 7;
    int base = (xcd < r) ? xcd * (q + 1) : r * (q + 1) + (xcd - r) * q;
    return base + (orig >> 3);
}

// pack fp32 -> (bf16_hi << 16) | bf16_lo
__device__ __forceinline__ uint32_t pack_hilo(float v) {
    uint32_t u = __float_as_uint(v);
    uint32_t hb = u & 0xFFFF0000u;
    float lo = v - __uint_as_float(hb);
    return hb | (__float_as_uint(lo) >> 16);
}

// Transpose x[nc,784] -> xt[1024,nc] (zero-padded 32x32 image layout).
__global__ __launch_bounds__(256) void transpose_x(
    const float* __restrict__ x, float* __restrict__ xt, int nc)
{
    __shared__ float t[64][65];
    const int tx = threadIdx.x & 63, ty = threadIdx.x >> 6;
    const int p0 = blockIdx.x * 64, n0 = blockIdx.y * 64;
    #pragma unroll
    for (int rr = 0; rr < 16; ++rr) {
        int nl = rr * 4 + ty;
        int pp = p0 + tx;
        int pr = pp >> 5, pc = pp & 31;
        float v = 0.f;
        if (pr >= 2 && pr < 30 && pc >= 2 && pc < 30)
            v = x[(size_t)(n0 + nl) * 784 + (pr - 2) * 28 + (pc - 2)];
        t[tx][nl] = v;
    }
    __syncthreads();
    #pragma unroll
    for (int rr = 0; rr < 16; ++rr) {
        int pl = rr * 4 + ty;
        xt[(size_t)(p0 + pl) * nc + n0 + tx] = t[pl][tx];
    }
}

// conv1(pad2)+relu+pool, row-streaming, 2 images/thread (float2),
// 3 channels per block. Writes p1 PACKED hi/lo (uint32 per value).
__global__ __launch_bounds__(256, 2) void conv1_bt(
    const float* __restrict__ xt, const float* __restrict__ c1w,
    const float* __restrict__ c1b, uint32_t* __restrict__ p1p, int nc)
{
    const int newid = xcd_swizzle(blockIdx.x, gridDim.x);
    const int grp = newid / 392, rem = newid - grp * 392;
    const int pass = rem / 196, pos = rem - pass * 196;
    const int py = pos / 14, px = pos - py * 14;
    const int img = grp * 512 + threadIdx.x * 2;
    const float* pb = xt + (size_t)((2 * py) * 32 + 2 * px) * nc + img;

    float2 acc[12];
    #pragma unroll
    for (int i = 0; i < 12; ++i) acc[i] = make_float2(0.f, 0.f);

    #pragma unroll
    for (int r = 0; r < 6; ++r) {
        float2 row[6];
        #pragma unroll
        for (int cc = 0; cc < 6; ++cc)
            row[cc] = *(const float2*)&pb[(size_t)(r * 32 + cc) * nc];
        #pragma unroll
        for (int c3 = 0; c3 < 3; ++c3) {
            const float* wp = c1w + (pass * 3 + c3) * 25;
            if (r <= 4) {
                #pragma unroll
                for (int kx = 0; kx < 5; ++kx) {
                    float w = wp[r * 5 + kx];
                    acc[c3*4+0].x += row[kx].x   * w;
                    acc[c3*4+0].y += row[kx].y   * w;
                    acc[c3*4+1].x += row[kx+1].x * w;
                    acc[c3*4+1].y += row[kx+1].y * w;
                }
            }
            if (r >= 1) {
                #pragma unroll
                for (int kx = 0; kx < 5; ++kx) {
                    float w = wp[(r - 1) * 5 + kx];
                    acc[c3*4+2].x += row[kx].x   * w;
                    acc[c3*4+2].y += row[kx].y   * w;
                    acc[c3*4+3].x += row[kx+1].x * w;
                    acc[c3*4+3].y += row[kx+1].y * w;
                }
            }
        }
    }
    #pragma unroll
    for (int c3 = 0; c3 < 3; ++c3) {
        int ch = pass * 3 + c3;
        float b = c1b[ch];
        float mx = fmaxf(fmaxf(acc[c3*4+0].x, acc[c3*4+1].x),
                         fmaxf(acc[c3*4+2].x, acc[c3*4+3].x)) + b;
        float my = fmaxf(fmaxf(acc[c3*4+0].y, acc[c3*4+1].y),
                         fmaxf(acc[c3*4+2].y, acc[c3*4+3].y)) + b;
        uint2 o2;
        o2.x = pack_hilo(fmaxf(mx, 0.f));
        o2.y = pack_hilo(fmaxf(my, 0.f));
        *(uint2*)&p1p[(size_t)(ch * 196 + pos) * nc + img] = o2;
    }
}

// conv2 via LDS-staged MFMA. Grid: flat 5*(nc/64), XCD-swizzled.
// block -> (rowpair rp 0..4, 64-img chunk). Loop ci: stage [84][64] packed
// dwords into LDS (stride 68), then each wave computes its 16-img group
// across 20 conv positions (1 kstep, K=25 padded to 32).
__global__ __launch_bounds__(256) void conv2_mfma(
    const uint32_t* __restrict__ p1p, const float* __restrict__ c2w,
    const float* __restrict__ c2b, float* __restrict__ ht, int nc)
{
    __shared__ uint32_t lds[84 * LSTRIDE + LSTRIDE];
    const int newid = xcd_swizzle(blockIdx.x, gridDim.x);
    const int grp = newid / 5, rp = newid - grp * 5;   // quad-row-pair 0..4
    const int tid = threadIdx.x;
    const int w = tid >> 6, lane = tid & 63;
    const int lhi = lane >> 4, llo = lane & 15;
    const int colbase = w * 16 + llo;
    const int imgbase = grp * 64;
    const int zaddr = 84 * LSTRIDE + colbase;          // zero pad region

    if (tid < LSTRIDE) lds[84 * LSTRIDE + tid] = 0;

    // per-lane k decomposition: j -> LDS feature offset (or invalid)
    int vbase[8]; bool valid[8];
    #pragma unroll
    for (int j = 0; j < 8; ++j) {
        int k = lhi * 8 + j;
        valid[j] = (k < 25);
        int kk = valid[j] ? k : 0;
        int ky = kk / 5, kx = kk - ky * 5;
        vbase[j] = (ky * 14 + kx) * LSTRIDE + colbase;
    }

    f32x4 acc[20];
    #pragma unroll
    for (int p = 0; p < 20; ++p) acc[p] = (f32x4)(0.f);

    #pragma unroll 1
    for (int ci = 0; ci < 6; ++ci) {
        __syncthreads();
        // stage 84 feat rows x 64 imgs (logical d = feat*64+img)
        {
            const uint32_t* src =
                p1p + (size_t)(ci * 196 + 28 * rp) * nc + imgbase;
            #pragma unroll
            for (int kk2 = 0; kk2 < 21; ++kk2) {
                int d = tid + kk2 * 256;
                lds[(d >> 6) * LSTRIDE + (d & 63)] =
                    src[(size_t)(d >> 6) * nc + (d & 63)];
            }
        }
        // A frags (weights hi/lo) for this ci
        bf16x8 wh, wl;
        {
            PackB ph, pl;
            #pragma unroll
            for (int j = 0; j < 8; ++j) {
                int k = lhi * 8 + j;
                float wv = (k < 25) ? c2w[(llo * 6 + ci) * 25 + k] : 0.f;
                uint32_t u  = __float_as_uint(wv);
                uint32_t hb = u & 0xFFFF0000u;
                float    lo = wv - __uint_as_float(hb);
                uint32_t lb = __float_as_uint(lo) & 0xFFFF0000u;
                if (j & 1) { ph.u[j >> 1] |= hb;       pl.u[j >> 1] |= lb; }
                else       { ph.u[j >> 1]  = hb >> 16; pl.u[j >> 1]  = lb >> 16; }
            }
            wh = ph.v; wl = pl.v;
        }
        __syncthreads();
        // 20 conv positions: pos = cyloc*10 + cx
        #pragma unroll
        for (int pos = 0; pos < 20; ++pos) {
            const int posoff = ((pos / 10) * 14 + (pos % 10)) * LSTRIDE;
            uint32_t wd[8];
            #pragma unroll
            for (int j = 0; j < 8; ++j)
                wd[j] = lds[valid[j] ? (vbase[j] + posoff) : zaddr];
            PackB bh, bl;
            #pragma unroll
            for (int i2 = 0; i2 < 4; ++i2) {
                bh.u[i2] = (wd[2*i2] >> 16)     | (wd[2*i2+1] & 0xFFFF0000u);
                bl.u[i2] = (wd[2*i2] & 0xFFFFu) | (wd[2*i2+1] << 16);
            }
            acc[pos] = __builtin_amdgcn_mfma_f32_16x16x32_bf16(
                           wh, bh.v, acc[pos], 0, 0, 0);
            acc[pos] = __builtin_amdgcn_mfma_f32_16x16x32_bf16(
                           wh, bl.v, acc[pos], 0, 0, 0);
            acc[pos] = __builtin_amdgcn_mfma_f32_16x16x32_bf16(
                           wl, bh.v, acc[pos], 0, 0, 0);
        }
    }
    // epilogue: 2x2 pool per quad + bias + relu + store
    float bias[4];
    #pragma unroll
    for (int r = 0; r < 4; ++r) bias[r] = c2b[lhi * 4 + r];
    #pragma unroll
    for (int q = 0; q < 5; ++q) {
        f32x4 m0 = acc[2*q],      m1 = acc[2*q + 1];
        f32x4 m2 = acc[10 + 2*q], m3 = acc[11 + 2*q];
        #pragma unroll
        for (int r = 0; r < 4; ++r) {
            int oc = lhi * 4 + r;
            float m = fmaxf(fmaxf(m0[r], m1[r]), fmaxf(m2[r], m3[r]));
            m = fmaxf(m + bias[r], 0.f);
            ht[(size_t)(oc * 25 + rp * 5 + q) * nc + imgbase + colbase] = m;
        }
    }
}

// fc1: a1t[o][n] = relu(sum_k ht[k][n]*f1w[o][k] + b). 2 img/thread.
__global__ __launch_bounds__(256) void fc1_bt(
    const float* __restrict__ ht, const float* __restrict__ f1w,
    const float* __restrict__ f1b, float* __restrict__ a1t, int nc)
{
    const int newid = xcd_swizzle(blockIdx.x, gridDim.x);
    const int grp = newid / 15, og = newid - grp * 15;
    const int img = grp * 512 + threadIdx.x * 2;
    const float* wb = f1w + og * 8 * 400;

    float2 acc[8];
    #pragma unroll
    for (int j = 0; j < 8; ++j) acc[j] = make_float2(0.f, 0.f);

    #pragma unroll 4
    for (int k = 0; k < 400; ++k) {
        float2 hv = *(const float2*)&ht[(size_t)k * nc + img];
        #pragma unroll
        for (int j = 0; j < 8; ++j) {
            float w = wb[j * 400 + k];
            acc[j].x += hv.x * w;
            acc[j].y += hv.y * w;
        }
    }
    #pragma unroll
    for (int j = 0; j < 8; ++j) {
        int o = og * 8 + j;
        float b = f1b[o];
        float2 o2 = make_float2(fmaxf(acc[j].x + b, 0.f),
                                fmaxf(acc[j].y + b, 0.f));
        *(float2*)&a1t[(size_t)o * nc + img] = o2;
    }
}

// fc2: a2t[o][n] = relu(sum_k a1t[k][n]*f2w[o][k] + b).
__global__ __launch_bounds__(256) void fc2_bt(
    const float* __restrict__ a1t, const float* __restrict__ f2w,
    const float* __restrict__ f2b, float* __restrict__ a2t, int nc)
{
    const int newid = xcd_swizzle(blockIdx.x, gridDim.x);
    const int grp = newid / 12, og = newid - grp * 12;
    const int img = grp * 512 + threadIdx.x * 2;
    const float* wb = f2w + og * 7 * 120;

    float2 acc[7];
    #pragma unroll
    for (int j = 0; j < 7; ++j) acc[j] = make_float2(0.f, 0.f);

    #pragma unroll 4
    for (int k = 0; k < 120; ++k) {
        float2 hv = *(const float2*)&a1t[(size_t)k * nc + img];
        #pragma unroll
        for (int j = 0; j < 7; ++j) {
            float w = wb[j * 120 + k];
            acc[j].x += hv.x * w;
            acc[j].y += hv.y * w;
        }
    }
    #pragma unroll
    for (int j = 0; j < 7; ++j) {
        int o = og * 7 + j;
        float b = f2b[o];
        float2 o2 = make_float2(fmaxf(acc[j].x + b, 0.f),
                                fmaxf(acc[j].y + b, 0.f));
        *(float2*)&a2t[(size_t)o * nc + img] = o2;
    }
}

// fc3 (no relu): embt[o][n0+n] = sum_k a2t[k][n]*f3w[o][k] + b.
__global__ __launch_bounds__(256) void fc3_bt(
    const float* __restrict__ a2t, const float* __restrict__ f3w,
    const float* __restrict__ f3b, float* __restrict__ embt,
    int nc, int Ntot, int n0)
{
    const int newid = xcd_swizzle(blockIdx.x, gridDim.x);
    const int grp = newid / 8, og = newid - grp * 8;
    const int limg = grp * 512 + threadIdx.x * 2;
    const float* wb = f3w + og * 8 * 84;

    float2 acc[8];
    #pragma unroll
    for (int j = 0; j < 8; ++j) acc[j] = make_float2(0.f, 0.f);

    #pragma unroll 4
    for (int k = 0; k < 84; ++k) {
        float2 hv = *(const float2*)&a2t[(size_t)k * nc + limg];
        #pragma unroll
        for (int j = 0; j < 8; ++j) {
            float w = wb[j * 84 + k];
            acc[j].x += hv.x * w;
            acc[j].y += hv.y * w;
        }
    }
    #pragma unroll
    for (int j = 0; j < 8; ++j) {
        int o = og * 8 + j;
        float b = f3b[o];
        float2 o2 = make_float2(acc[j].x + b, acc[j].y + b);
        *(float2*)&embt[(size_t)o * Ntot + n0 + limg] = o2;
    }
}

// Head: thread = image. Serial 64-wide softmax in registers.
__global__ __launch_bounds__(256) void proto_head_t(
    const float* __restrict__ embt, float* __restrict__ out, int N)
{
    const int img = blockIdx.x * 256 + threadIdx.x;
    float v[64];
    float m = -1e30f;
    #pragma unroll
    for (int o = 0; o < 64; ++o) {
        v[o] = embt[(size_t)o * N + img];
        m = fmaxf(m, v[o]);
    }
    float s = 0.f;
    #pragma unroll
    for (int o = 0; o < 64; ++o) {
        v[o] = __expf(v[o] - m);
        s += v[o];
    }
    float inv = __frcp_rn(s);
    #pragma unroll
    for (int o = 0; o < 64; o += 4) {
        float4 r;
        r.x = fabsf(v[o+0] * inv - embt[(size_t)(o+0) * N] * 0.2f);
        r.y = fabsf(v[o+1] * inv - embt[(size_t)(o+1) * N] * 0.2f);
        r.z = fabsf(v[o+2] * inv - embt[(size_t)(o+2) * N] * 0.2f);
        r.w = fabsf(v[o+3] * inv - embt[(size_t)(o+3) * N] * 0.2f);
        *(float4*)&out[(size_t)img * 64 + o] = r;
    }
}

extern "C" void kernel_launch(void* const* d_in, const int* in_sizes, int n_in,
                              void* d_out, int out_size, void* d_ws, size_t ws_size,
                              hipStream_t stream)
{
    const float* x   = (const float*)d_in[0];
    const float* c1w = (const float*)d_in[1];
    const float* c1b = (const float*)d_in[2];
    const float* c2w = (const float*)d_in[3];
    const float* c2b = (const float*)d_in[4];
    const float* f1w = (const float*)d_in[5];
    const float* f1b = (const float*)d_in[6];
    const float* f2w = (const float*)d_in[7];
    const float* f2b = (const float*)d_in[8];
    const float* f3w = (const float*)d_in[9];
    const float* f3b = (const float*)d_in[10];
    float* out = (float*)d_out;

    const int N = in_sizes[0] / 784;          // 20480
    float* base = (float*)d_ws;

    int c = 40;
    const int cands[] = {1, 2, 4, 5, 8, 10, 20, 40};
    for (int k = 0; k < 8; ++k) {
        int cd = cands[k];
        if (N % cd) continue;
        int ncq = N / cd;
        if (ncq % 512) continue;
        size_t need = (size_t)8800 * ncq + (size_t)256 * N;
        if (need <= ws_size) { c = cd; break; }
    }
    const int nc = N / c;

    float*    xt   = base;                        // [1024][nc]
    uint32_t* p1p  = (uint32_t*)(base + (size_t)1024 * nc);  // [1176][nc]
    float*    ht_  = base;                        // [400][nc] (over xt)
    float*    a1t  = (float*)p1p;                 // [120][nc] (over p1p)
    float*    a2t  = (float*)p1p + (size_t)120 * nc;  // [84][nc]
    float*    embt = base + (size_t)2200 * nc;    // [64][N]

    for (int k = 0; k < c; ++k) {
        int n0 = k * nc;
        transpose_x<<<dim3(16, nc / 64), 256, 0, stream>>>(
            x + (size_t)n0 * 784, xt, nc);
        conv1_bt<<<392 * (nc / 512), 256, 0, stream>>>(
            xt, c1w, c1b, p1p, nc);
        conv2_mfma<<<5 * (nc / 64), 256, 0, stream>>>(
            p1p, c2w, c2b, ht_, nc);
        fc1_bt<<<15 * (nc / 512), 256, 0, stream>>>(
            ht_, f1w, f1b, a1t, nc);
        fc2_bt<<<12 * (nc / 512), 256, 0, stream>>>(
            a1t, f2w, f2b, a2t, nc);
        fc3_bt<<<8 * (nc / 512), 256, 0, stream>>>(
            a2t, f3w, f3b, embt, nc, N, n0);
    }
    proto_head_t<<<N / 256, 256, 0, stream>>>(embt, out, N);
}

// Round 14
// 281.878 us; speedup vs baseline: 1.6399x; 1.6399x over previous
//
#include <hip/hip_runtime.h>

// ---------------------------------------------------------------------------
// Batch-inner LeNet: lane = image, activations in [feature][N] layout.
// All weights are wave-uniform -> scalar loads (s_load, SGPR operands);
// zero LDS outside the transpose. XCD swizzle keeps an image-group's
// activations resident in one XCD's L2.  (Consolidation of R7 = measured
// best 288.6 us; single delta: conv2 oc-pass split across blocks.)
// MFMA retrospective (R12/R13): concept numerically proven but B-operand
// k-strided scalar reads swamp the matrix pipe (MfmaUtil ~5%); reverted.
// ---------------------------------------------------------------------------

__device__ __forceinline__ int xcd_swizzle(int orig, int nwg) {
    // m204 bijective: xcd = orig%8 gets a contiguous newid range.
    int xcd = orig & 7, q = nwg >> 3, r = nwg & 7;
    int base = (xcd < r) ? xcd * (q + 1) : r * (q + 1) + (xcd - r) * q;
    return base + (orig >> 3);
}

// Transpose x[nc,784] -> xt[1024,nc] (zero-padded 32x32 image layout).
// grid = (16, nc/64).
__global__ __launch_bounds__(256) void transpose_x(
    const float* __restrict__ x, float* __restrict__ xt, int nc)
{
    __shared__ float t[64][65];
    const int tx = threadIdx.x & 63, ty = threadIdx.x >> 6;  // ty 0..3
    const int p0 = blockIdx.x * 64, n0 = blockIdx.y * 64;
    #pragma unroll
    for (int rr = 0; rr < 16; ++rr) {
        int nl = rr * 4 + ty;
        int pp = p0 + tx;              // padded pixel 0..1023
        int pr = pp >> 5, pc = pp & 31;
        float v = 0.f;
        if (pr >= 2 && pr < 30 && pc >= 2 && pc < 30)
            v = x[(size_t)(n0 + nl) * 784 + (pr - 2) * 28 + (pc - 2)];
        t[tx][nl] = v;
    }
    __syncthreads();
    #pragma unroll
    for (int rr = 0; rr < 16; ++rr) {
        int pl = rr * 4 + ty;
        xt[(size_t)(p0 + pl) * nc + n0 + tx] = t[pl][tx];
    }
}

// conv1(pad2)+relu+pool. Flat grid = 196*(nc/512); 2 consecutive images per
// thread via float2. Weights via scalar pipe.
__global__ __launch_bounds__(256, 1) void conv1_bt(
    const float* __restrict__ xt, const float* __restrict__ c1w,
    const float* __restrict__ c1b, float* __restrict__ p1t, int nc)
{
    const int newid = xcd_swizzle(blockIdx.x, gridDim.x);
    const int grp = newid / 196, pos = newid - grp * 196;
    const int py = pos / 14, px = pos - py * 14;
    const int img = grp * 512 + threadIdx.x * 2;
    const int pbase = (2 * py) * 32 + 2 * px; // top-left of 6x6 in padded img

    float2 p[36];
    #pragma unroll
    for (int r = 0; r < 6; ++r)
        #pragma unroll
        for (int cc = 0; cc < 6; ++cc)
            p[r * 6 + cc] =
                *(const float2*)&xt[(size_t)(pbase + r * 32 + cc) * nc + img];

    #pragma unroll
    for (int ch = 0; ch < 6; ++ch) {
        float w[25];
        const float* wp = c1w + ch * 25;     // uniform -> s_load
        #pragma unroll
        for (int k = 0; k < 25; ++k) w[k] = wp[k];
        float b = c1b[ch];
        float ma = -1e30f, mb = -1e30f;
        #pragma unroll
        for (int dy = 0; dy < 2; ++dy)
        #pragma unroll
        for (int dx = 0; dx < 2; ++dx) {
            float aa = b, ab = b;
            #pragma unroll
            for (int ky = 0; ky < 5; ++ky)
            #pragma unroll
            for (int kx = 0; kx < 5; ++kx) {
                float ww = w[ky * 5 + kx];
                float2 pv = p[(dy + ky) * 6 + dx + kx];
                aa += pv.x * ww;
                ab += pv.y * ww;
            }
            ma = fmaxf(ma, aa); mb = fmaxf(mb, ab);
        }
        float2 o2 = make_float2(fmaxf(ma, 0.f), fmaxf(mb, 0.f));
        *(float2*)&p1t[(size_t)(ch * 196 + pos) * nc + img] = o2;
    }
}

// conv2(valid)+relu+pool: 2 images/thread (float2), 8 oc per BLOCK (pass is
// a blockIdx component -> 2x blocks vs R7 for latency hiding / tail).
// Same 44:1 FMA:load body as R7's 114us kernel. Flat grid = 50*(nc/512),
// XCD-swizzled (group window 2.4 MB <= 4 MB L2 -> pass re-reads L2-local).
// Feature order ch*25 + qy*5 + qx matches reference flatten.
__global__ __launch_bounds__(256, 1) void conv2_bt(
    const float* __restrict__ p1t, const float* __restrict__ c2w,
    const float* __restrict__ c2b, float* __restrict__ ht, int nc)
{
    const int newid = xcd_swizzle(blockIdx.x, gridDim.x);
    const int grp = newid / 50, rem = newid - grp * 50;
    const int pass = rem / 25, pos = rem - pass * 25;
    const int qy = pos / 5, qx = pos - qy * 5;
    const int img = grp * 512 + threadIdx.x * 2;
    const int y0 = 2 * qy, x0 = 2 * qx;

    float2 acc[32];                      // [o8][quad], 2 imgs packed
    #pragma unroll
    for (int i = 0; i < 32; ++i) acc[i] = make_float2(0.f, 0.f);

    #pragma unroll 1
    for (int ci = 0; ci < 6; ++ci) {
        float2 pa[36];
        #pragma unroll
        for (int r = 0; r < 6; ++r)
            #pragma unroll
            for (int cc = 0; cc < 6; ++cc)
                pa[r * 6 + cc] = *(const float2*)
                    &p1t[(size_t)(ci * 196 + (y0 + r) * 14 + x0 + cc) * nc + img];
        #pragma unroll
        for (int o8 = 0; o8 < 8; ++o8) {
            float w[25];
            const float* wp = c2w + ((pass * 8 + o8) * 6 + ci) * 25;
            #pragma unroll
            for (int k = 0; k < 25; ++k) w[k] = wp[k];
            #pragma unroll
            for (int ky = 0; ky < 5; ++ky)
            #pragma unroll
            for (int kx = 0; kx < 5; ++kx) {
                float ww = w[ky * 5 + kx];
                float2 p00 = pa[ky*6+kx];
                float2 p01 = pa[ky*6+kx+1];
                float2 p10 = pa[(ky+1)*6+kx];
                float2 p11 = pa[(ky+1)*6+kx+1];
                acc[o8*4+0].x += p00.x * ww; acc[o8*4+0].y += p00.y * ww;
                acc[o8*4+1].x += p01.x * ww; acc[o8*4+1].y += p01.y * ww;
                acc[o8*4+2].x += p10.x * ww; acc[o8*4+2].y += p10.y * ww;
                acc[o8*4+3].x += p11.x * ww; acc[o8*4+3].y += p11.y * ww;
            }
        }
    }
    #pragma unroll
    for (int o8 = 0; o8 < 8; ++o8) {
        int oc = pass * 8 + o8;
        float b = c2b[oc];
        float mx = fmaxf(fmaxf(acc[o8*4+0].x, acc[o8*4+1].x),
                         fmaxf(acc[o8*4+2].x, acc[o8*4+3].x)) + b;
        float my = fmaxf(fmaxf(acc[o8*4+0].y, acc[o8*4+1].y),
                         fmaxf(acc[o8*4+2].y, acc[o8*4+3].y)) + b;
        float2 o2 = make_float2(fmaxf(mx, 0.f), fmaxf(my, 0.f));
        *(float2*)&ht[(size_t)(oc * 25 + pos) * nc + img] = o2;
    }
}

// fc1: a1t[o][n] = relu(sum_k ht[k][n]*f1w[o][k] + b). 2 img/thread (float2),
// 8 outs/block-group. Flat grid = 15*(nc/512), XCD-swizzled.
__global__ __launch_bounds__(256) void fc1_bt(
    const float* __restrict__ ht, const float* __restrict__ f1w,
    const float* __restrict__ f1b, float* __restrict__ a1t, int nc)
{
    const int newid = xcd_swizzle(blockIdx.x, gridDim.x);
    const int grp = newid / 15, og = newid - grp * 15;
    const int img = grp * 512 + threadIdx.x * 2;
    const float* wb = f1w + og * 8 * 400;

    float2 acc[8];
    #pragma unroll
    for (int j = 0; j < 8; ++j) acc[j] = make_float2(0.f, 0.f);

    #pragma unroll 4
    for (int k = 0; k < 400; ++k) {
        float2 hv = *(const float2*)&ht[(size_t)k * nc + img];
        #pragma unroll
        for (int j = 0; j < 8; ++j) {
            float w = wb[j * 400 + k];        // uniform -> s_load
            acc[j].x += hv.x * w;
            acc[j].y += hv.y * w;
        }
    }
    #pragma unroll
    for (int j = 0; j < 8; ++j) {
        int o = og * 8 + j;
        float b = f1b[o];
        float2 o2 = make_float2(fmaxf(acc[j].x + b, 0.f),
                                fmaxf(acc[j].y + b, 0.f));
        *(float2*)&a1t[(size_t)o * nc + img] = o2;
    }
}

// fc2: a2t[o][n] = relu(sum_k a1t[k][n]*f2w[o][k] + b). 7 outs x 12 groups.
__global__ __launch_bounds__(256) void fc2_bt(
    const float* __restrict__ a1t, const float* __restrict__ f2w,
    const float* __restrict__ f2b, float* __restrict__ a2t, int nc)
{
    const int newid = xcd_swizzle(blockIdx.x, gridDim.x);
    const int grp = newid / 12, og = newid - grp * 12;
    const int img = grp * 512 + threadIdx.x * 2;
    const float* wb = f2w + og * 7 * 120;

    float2 acc[7];
    #pragma unroll
    for (int j = 0; j < 7; ++j) acc[j] = make_float2(0.f, 0.f);

    #pragma unroll 4
    for (int k = 0; k < 120; ++k) {
        float2 hv = *(const float2*)&a1t[(size_t)k * nc + img];
        #pragma unroll
        for (int j = 0; j < 7; ++j) {
            float w = wb[j * 120 + k];
            acc[j].x += hv.x * w;
            acc[j].y += hv.y * w;
        }
    }
    #pragma unroll
    for (int j = 0; j < 7; ++j) {
        int o = og * 7 + j;
        float b = f2b[o];
        float2 o2 = make_float2(fmaxf(acc[j].x + b, 0.f),
                                fmaxf(acc[j].y + b, 0.f));
        *(float2*)&a2t[(size_t)o * nc + img] = o2;
    }
}

// fc3 (no relu): embt[o][n0+n] = sum_k a2t[k][n]*f3w[o][k] + b.
// embt is the FULL-N buffer [64][Ntot]; chunk writes at offset n0.
__global__ __launch_bounds__(256) void fc3_bt(
    const float* __restrict__ a2t, const float* __restrict__ f3w,
    const float* __restrict__ f3b, float* __restrict__ embt,
    int nc, int Ntot, int n0)
{
    const int newid = xcd_swizzle(blockIdx.x, gridDim.x);
    const int grp = newid / 8, og = newid - grp * 8;
    const int limg = grp * 512 + threadIdx.x * 2;
    const float* wb = f3w + og * 8 * 84;

    float2 acc[8];
    #pragma unroll
    for (int j = 0; j < 8; ++j) acc[j] = make_float2(0.f, 0.f);

    #pragma unroll 4
    for (int k = 0; k < 84; ++k) {
        float2 hv = *(const float2*)&a2t[(size_t)k * nc + limg];
        #pragma unroll
        for (int j = 0; j < 8; ++j) {
            float w = wb[j * 84 + k];
            acc[j].x += hv.x * w;
            acc[j].y += hv.y * w;
        }
    }
    #pragma unroll
    for (int j = 0; j < 8; ++j) {
        int o = og * 8 + j;
        float b = f3b[o];
        float2 o2 = make_float2(acc[j].x + b, acc[j].y + b);
        *(float2*)&embt[(size_t)o * Ntot + n0 + limg] = o2;
    }
}

// Head: thread = image. Serial 64-wide softmax in registers; proto via
// uniform s_load of embt[o][0]. Stores 64 consecutive floats per thread.
__global__ __launch_bounds__(256) void proto_head_t(
    const float* __restrict__ embt, float* __restrict__ out, int N)
{
    const int img = blockIdx.x * 256 + threadIdx.x;
    float v[64];
    float m = -1e30f;
    #pragma unroll
    for (int o = 0; o < 64; ++o) {
        v[o] = embt[(size_t)o * N + img];
        m = fmaxf(m, v[o]);
    }
    float s = 0.f;
    #pragma unroll
    for (int o = 0; o < 64; ++o) {
        v[o] = __expf(v[o] - m);
        s += v[o];
    }
    float inv = __frcp_rn(s);
    #pragma unroll
    for (int o = 0; o < 64; o += 4) {
        float4 r;
        r.x = fabsf(v[o+0] * inv - embt[(size_t)(o+0) * N] * 0.2f);
        r.y = fabsf(v[o+1] * inv - embt[(size_t)(o+1) * N] * 0.2f);
        r.z = fabsf(v[o+2] * inv - embt[(size_t)(o+2) * N] * 0.2f);
        r.w = fabsf(v[o+3] * inv - embt[(size_t)(o+3) * N] * 0.2f);
        *(float4*)&out[(size_t)img * 64 + o] = r;
    }
}

extern "C" void kernel_launch(void* const* d_in, const int* in_sizes, int n_in,
                              void* d_out, int out_size, void* d_ws, size_t ws_size,
                              hipStream_t stream)
{
    const float* x   = (const float*)d_in[0];
    const float* c1w = (const float*)d_in[1];
    const float* c1b = (const float*)d_in[2];
    const float* c2w = (const float*)d_in[3];
    const float* c2b = (const float*)d_in[4];
    const float* f1w = (const float*)d_in[5];
    const float* f1b = (const float*)d_in[6];
    const float* f2w = (const float*)d_in[7];
    const float* f2b = (const float*)d_in[8];
    const float* f3w = (const float*)d_in[9];
    const float* f3b = (const float*)d_in[10];
    float* out = (float*)d_out;

    const int N = in_sizes[0] / 784;          // 20480
    float* base = (float*)d_ws;

    // Region A: xt[1024][nc] -> reused as ht[400][nc]
    // Region B: p1t[1176][nc] -> reused as a1t[120][nc] + a2t[84][nc]
    // embt[64][N] persistent.  bytes = 8800nc + 256N
    int c = 40;
    const int cands[] = {1, 2, 4, 5, 8, 10, 20, 40};
    for (int k = 0; k < 8; ++k) {
        int cd = cands[k];
        if (N % cd) continue;
        int ncq = N / cd;
        if (ncq % 512) continue;
        size_t need = (size_t)8800 * ncq + (size_t)256 * N;
        if (need <= ws_size) { c = cd; break; }
    }
    const int nc = N / c;

    float* xt   = base;                        // [1024][nc] padded images
    float* p1t  = base + (size_t)1024 * nc;    // [1176][nc]
    float* ht_  = base;                        // [400][nc]  (over xt)
    float* a1t  = p1t;                         // [120][nc]  (over p1t)
    float* a2t  = p1t + (size_t)120 * nc;      // [84][nc]
    float* embt = base + (size_t)2200 * nc;    // [64][N]

    for (int k = 0; k < c; ++k) {
        int n0 = k * nc;
        transpose_x<<<dim3(16, nc / 64), 256, 0, stream>>>(
            x + (size_t)n0 * 784, xt, nc);
        conv1_bt<<<196 * (nc / 512), 256, 0, stream>>>(
            xt, c1w, c1b, p1t, nc);
        conv2_bt<<<50 * (nc / 512), 256, 0, stream>>>(
            p1t, c2w, c2b, ht_, nc);
        fc1_bt<<<15 * (nc / 512), 256, 0, stream>>>(
            ht_, f1w, f1b, a1t, nc);
        fc2_bt<<<12 * (nc / 512), 256, 0, stream>>>(
            a1t, f2w, f2b, a2t, nc);
        fc3_bt<<<8 * (nc / 512), 256, 0, stream>>>(
            a2t, f3w, f3b, embt, nc, N, n0);
    }
    proto_head_t<<<N / 256, 256, 0, stream>>>(embt, out, N);
}

// Round 15
// 268.998 us; speedup vs baseline: 1.7184x; 1.0479x over previous
//
#include <hip/hip_runtime.h>

// ---------------------------------------------------------------------------
// Batch-inner LeNet: lane = image, activations in [feature][N] layout.
// R15 delta vs R14 (best, 281.9us): all hot-loop float2 component math
// rewritten as clang ext_vector float2 arithmetic so LLVM keeps <2 x float>
// FMAs and selects v_pk_fma_f32 (VOP3P, 2 fp32 FMA/lane/instr) -> halves
// VALU instruction count in conv1/conv2/fc1/fc2/fc3. Memory pattern, grids,
// numerics identical (pk_fma = IEEE fp32 FMA per half).
// ---------------------------------------------------------------------------

typedef __attribute__((ext_vector_type(2))) float f32x2;

__device__ __forceinline__ int xcd_swizzle(int orig, int nwg) {
    // m204 bijective: xcd = orig%8 gets a contiguous newid range.
    int xcd = orig & 7, q = nwg >> 3, r = nwg & 7;
    int base = (xcd < r) ? xcd * (q + 1) : r * (q + 1) + (xcd - r) * q;
    return base + (orig >> 3);
}

// Transpose x[nc,784] -> xt[1024,nc] (zero-padded 32x32 image layout).
// grid = (16, nc/64).
__global__ __launch_bounds__(256) void transpose_x(
    const float* __restrict__ x, float* __restrict__ xt, int nc)
{
    __shared__ float t[64][65];
    const int tx = threadIdx.x & 63, ty = threadIdx.x >> 6;  // ty 0..3
    const int p0 = blockIdx.x * 64, n0 = blockIdx.y * 64;
    #pragma unroll
    for (int rr = 0; rr < 16; ++rr) {
        int nl = rr * 4 + ty;
        int pp = p0 + tx;              // padded pixel 0..1023
        int pr = pp >> 5, pc = pp & 31;
        float v = 0.f;
        if (pr >= 2 && pr < 30 && pc >= 2 && pc < 30)
            v = x[(size_t)(n0 + nl) * 784 + (pr - 2) * 28 + (pc - 2)];
        t[tx][nl] = v;
    }
    __syncthreads();
    #pragma unroll
    for (int rr = 0; rr < 16; ++rr) {
        int pl = rr * 4 + ty;
        xt[(size_t)(p0 + pl) * nc + n0 + tx] = t[pl][tx];
    }
}

// conv1(pad2)+relu+pool. Flat grid = 196*(nc/512); 2 consecutive images per
// thread (f32x2, packed FMA). Weights via scalar pipe.
__global__ __launch_bounds__(256, 1) void conv1_bt(
    const float* __restrict__ xt, const float* __restrict__ c1w,
    const float* __restrict__ c1b, float* __restrict__ p1t, int nc)
{
    const int newid = xcd_swizzle(blockIdx.x, gridDim.x);
    const int grp = newid / 196, pos = newid - grp * 196;
    const int py = pos / 14, px = pos - py * 14;
    const int img = grp * 512 + threadIdx.x * 2;
    const int pbase = (2 * py) * 32 + 2 * px; // top-left of 6x6 in padded img

    f32x2 p[36];
    #pragma unroll
    for (int r = 0; r < 6; ++r)
        #pragma unroll
        for (int cc = 0; cc < 6; ++cc)
            p[r * 6 + cc] =
                *(const f32x2*)&xt[(size_t)(pbase + r * 32 + cc) * nc + img];

    #pragma unroll
    for (int ch = 0; ch < 6; ++ch) {
        float w[25];
        const float* wp = c1w + ch * 25;     // uniform -> s_load
        #pragma unroll
        for (int k = 0; k < 25; ++k) w[k] = wp[k];
        float b = c1b[ch];
        f32x2 m01 = (f32x2)(-1e30f);
        #pragma unroll
        for (int dy = 0; dy < 2; ++dy)
        #pragma unroll
        for (int dx = 0; dx < 2; ++dx) {
            f32x2 a = (f32x2)(b);
            #pragma unroll
            for (int ky = 0; ky < 5; ++ky)
            #pragma unroll
            for (int kx = 0; kx < 5; ++kx)
                a += p[(dy + ky) * 6 + dx + kx] * w[ky * 5 + kx];
            m01.x = fmaxf(m01.x, a.x);
            m01.y = fmaxf(m01.y, a.y);
        }
        f32x2 o2;
        o2.x = fmaxf(m01.x, 0.f);
        o2.y = fmaxf(m01.y, 0.f);
        *(f32x2*)&p1t[(size_t)(ch * 196 + pos) * nc + img] = o2;
    }
}

// conv2(valid)+relu+pool: 2 images/thread (f32x2, packed FMA), 8 oc/block
// (pass in blockIdx). Flat grid = 50*(nc/512), XCD-swizzled (group window
// 2.4 MB <= 4 MB L2). Feature order ch*25 + qy*5 + qx.
__global__ __launch_bounds__(256, 1) void conv2_bt(
    const float* __restrict__ p1t, const float* __restrict__ c2w,
    const float* __restrict__ c2b, float* __restrict__ ht, int nc)
{
    const int newid = xcd_swizzle(blockIdx.x, gridDim.x);
    const int grp = newid / 50, rem = newid - grp * 50;
    const int pass = rem / 25, pos = rem - pass * 25;
    const int qy = pos / 5, qx = pos - qy * 5;
    const int img = grp * 512 + threadIdx.x * 2;
    const int y0 = 2 * qy, x0 = 2 * qx;

    f32x2 acc[32];                      // [o8][quad], 2 imgs packed
    #pragma unroll
    for (int i = 0; i < 32; ++i) acc[i] = (f32x2)(0.f);

    #pragma unroll 1
    for (int ci = 0; ci < 6; ++ci) {
        f32x2 pa[36];
        #pragma unroll
        for (int r = 0; r < 6; ++r)
            #pragma unroll
            for (int cc = 0; cc < 6; ++cc)
                pa[r * 6 + cc] = *(const f32x2*)
                    &p1t[(size_t)(ci * 196 + (y0 + r) * 14 + x0 + cc) * nc + img];
        #pragma unroll
        for (int o8 = 0; o8 < 8; ++o8) {
            float w[25];
            const float* wp = c2w + ((pass * 8 + o8) * 6 + ci) * 25;
            #pragma unroll
            for (int k = 0; k < 25; ++k) w[k] = wp[k];
            #pragma unroll
            for (int ky = 0; ky < 5; ++ky)
            #pragma unroll
            for (int kx = 0; kx < 5; ++kx) {
                float ww = w[ky * 5 + kx];
                acc[o8*4+0] += pa[ky*6+kx]       * ww;
                acc[o8*4+1] += pa[ky*6+kx+1]     * ww;
                acc[o8*4+2] += pa[(ky+1)*6+kx]   * ww;
                acc[o8*4+3] += pa[(ky+1)*6+kx+1] * ww;
            }
        }
    }
    #pragma unroll
    for (int o8 = 0; o8 < 8; ++o8) {
        int oc = pass * 8 + o8;
        float b = c2b[oc];
        float mx = fmaxf(fmaxf(acc[o8*4+0].x, acc[o8*4+1].x),
                         fmaxf(acc[o8*4+2].x, acc[o8*4+3].x)) + b;
        float my = fmaxf(fmaxf(acc[o8*4+0].y, acc[o8*4+1].y),
                         fmaxf(acc[o8*4+2].y, acc[o8*4+3].y)) + b;
        f32x2 o2;
        o2.x = fmaxf(mx, 0.f);
        o2.y = fmaxf(my, 0.f);
        *(f32x2*)&ht[(size_t)(oc * 25 + pos) * nc + img] = o2;
    }
}

// fc1: a1t[o][n] = relu(sum_k ht[k][n]*f1w[o][k] + b). 2 img/thread (f32x2),
// 8 outs/block-group. Flat grid = 15*(nc/512), XCD-swizzled.
__global__ __launch_bounds__(256) void fc1_bt(
    const float* __restrict__ ht, const float* __restrict__ f1w,
    const float* __restrict__ f1b, float* __restrict__ a1t, int nc)
{
    const int newid = xcd_swizzle(blockIdx.x, gridDim.x);
    const int grp = newid / 15, og = newid - grp * 15;
    const int img = grp * 512 + threadIdx.x * 2;
    const float* wb = f1w + og * 8 * 400;

    f32x2 acc[8];
    #pragma unroll
    for (int j = 0; j < 8; ++j) acc[j] = (f32x2)(0.f);

    #pragma unroll 4
    for (int k = 0; k < 400; ++k) {
        f32x2 hv = *(const f32x2*)&ht[(size_t)k * nc + img];
        #pragma unroll
        for (int j = 0; j < 8; ++j)
            acc[j] += hv * wb[j * 400 + k];   // uniform w -> s_load
    }
    #pragma unroll
    for (int j = 0; j < 8; ++j) {
        int o = og * 8 + j;
        float b = f1b[o];
        f32x2 o2;
        o2.x = fmaxf(acc[j].x + b, 0.f);
        o2.y = fmaxf(acc[j].y + b, 0.f);
        *(f32x2*)&a1t[(size_t)o * nc + img] = o2;
    }
}

// fc2: a2t[o][n] = relu(sum_k a1t[k][n]*f2w[o][k] + b). 7 outs x 12 groups.
__global__ __launch_bounds__(256) void fc2_bt(
    const float* __restrict__ a1t, const float* __restrict__ f2w,
    const float* __restrict__ f2b, float* __restrict__ a2t, int nc)
{
    const int newid = xcd_swizzle(blockIdx.x, gridDim.x);
    const int grp = newid / 12, og = newid - grp * 12;
    const int img = grp * 512 + threadIdx.x * 2;
    const float* wb = f2w + og * 7 * 120;

    f32x2 acc[7];
    #pragma unroll
    for (int j = 0; j < 7; ++j) acc[j] = (f32x2)(0.f);

    #pragma unroll 4
    for (int k = 0; k < 120; ++k) {
        f32x2 hv = *(const f32x2*)&a1t[(size_t)k * nc + img];
        #pragma unroll
        for (int j = 0; j < 7; ++j)
            acc[j] += hv * wb[j * 120 + k];
    }
    #pragma unroll
    for (int j = 0; j < 7; ++j) {
        int o = og * 7 + j;
        float b = f2b[o];
        f32x2 o2;
        o2.x = fmaxf(acc[j].x + b, 0.f);
        o2.y = fmaxf(acc[j].y + b, 0.f);
        *(f32x2*)&a2t[(size_t)o * nc + img] = o2;
    }
}

// fc3 (no relu): embt[o][n0+n] = sum_k a2t[k][n]*f3w[o][k] + b.
// embt is the FULL-N buffer [64][Ntot]; chunk writes at offset n0.
__global__ __launch_bounds__(256) void fc3_bt(
    const float* __restrict__ a2t, const float* __restrict__ f3w,
    const float* __restrict__ f3b, float* __restrict__ embt,
    int nc, int Ntot, int n0)
{
    const int newid = xcd_swizzle(blockIdx.x, gridDim.x);
    const int grp = newid / 8, og = newid - grp * 8;
    const int limg = grp * 512 + threadIdx.x * 2;
    const float* wb = f3w + og * 8 * 84;

    f32x2 acc[8];
    #pragma unroll
    for (int j = 0; j < 8; ++j) acc[j] = (f32x2)(0.f);

    #pragma unroll 4
    for (int k = 0; k < 84; ++k) {
        f32x2 hv = *(const f32x2*)&a2t[(size_t)k * nc + limg];
        #pragma unroll
        for (int j = 0; j < 8; ++j)
            acc[j] += hv * wb[j * 84 + k];
    }
    #pragma unroll
    for (int j = 0; j < 8; ++j) {
        int o = og * 8 + j;
        float b = f3b[o];
        f32x2 o2 = acc[j] + b;
        *(f32x2*)&embt[(size_t)o * Ntot + n0 + limg] = o2;
    }
}

// Head: thread = image. Serial 64-wide softmax in registers; proto via
// uniform s_load of embt[o][0]. Stores 64 consecutive floats per thread.
__global__ __launch_bounds__(256) void proto_head_t(
    const float* __restrict__ embt, float* __restrict__ out, int N)
{
    const int img = blockIdx.x * 256 + threadIdx.x;
    float v[64];
    float m = -1e30f;
    #pragma unroll
    for (int o = 0; o < 64; ++o) {
        v[o] = embt[(size_t)o * N + img];
        m = fmaxf(m, v[o]);
    }
    float s = 0.f;
    #pragma unroll
    for (int o = 0; o < 64; ++o) {
        v[o] = __expf(v[o] - m);
        s += v[o];
    }
    float inv = __frcp_rn(s);
    #pragma unroll
    for (int o = 0; o < 64; o += 4) {
        float4 r;
        r.x = fabsf(v[o+0] * inv - embt[(size_t)(o+0) * N] * 0.2f);
        r.y = fabsf(v[o+1] * inv - embt[(size_t)(o+1) * N] * 0.2f);
        r.z = fabsf(v[o+2] * inv - embt[(size_t)(o+2) * N] * 0.2f);
        r.w = fabsf(v[o+3] * inv - embt[(size_t)(o+3) * N] * 0.2f);
        *(float4*)&out[(size_t)img * 64 + o] = r;
    }
}

extern "C" void kernel_launch(void* const* d_in, const int* in_sizes, int n_in,
                              void* d_out, int out_size, void* d_ws, size_t ws_size,
                              hipStream_t stream)
{
    const float* x   = (const float*)d_in[0];
    const float* c1w = (const float*)d_in[1];
    const float* c1b = (const float*)d_in[2];
    const float* c2w = (const float*)d_in[3];
    const float* c2b = (const float*)d_in[4];
    const float* f1w = (const float*)d_in[5];
    const float* f1b = (const float*)d_in[6];
    const float* f2w = (const float*)d_in[7];
    const float* f2b = (const float*)d_in[8];
    const float* f3w = (const float*)d_in[9];
    const float* f3b = (const float*)d_in[10];
    float* out = (float*)d_out;

    const int N = in_sizes[0] / 784;          // 20480
    float* base = (float*)d_ws;

    // Region A: xt[1024][nc] -> reused as ht[400][nc]
    // Region B: p1t[1176][nc] -> reused as a1t[120][nc] + a2t[84][nc]
    // embt[64][N] persistent.  bytes = 8800nc + 256N
    int c = 40;
    const int cands[] = {1, 2, 4, 5, 8, 10, 20, 40};
    for (int k = 0; k < 8; ++k) {
        int cd = cands[k];
        if (N % cd) continue;
        int ncq = N / cd;
        if (ncq % 512) continue;
        size_t need = (size_t)8800 * ncq + (size_t)256 * N;
        if (need <= ws_size) { c = cd; break; }
    }
    const int nc = N / c;

    float* xt   = base;                        // [1024][nc] padded images
    float* p1t  = base + (size_t)1024 * nc;    // [1176][nc]
    float* ht_  = base;                        // [400][nc]  (over xt)
    float* a1t  = p1t;                         // [120][nc]  (over p1t)
    float* a2t  = p1t + (size_t)120 * nc;      // [84][nc]
    float* embt = base + (size_t)2200 * nc;    // [64][N]

    for (int k = 0; k < c; ++k) {
        int n0 = k * nc;
        transpose_x<<<dim3(16, nc / 64), 256, 0, stream>>>(
            x + (size_t)n0 * 784, xt, nc);
        conv1_bt<<<196 * (nc / 512), 256, 0, stream>>>(
            xt, c1w, c1b, p1t, nc);
        conv2_bt<<<50 * (nc / 512), 256, 0, stream>>>(
            p1t, c2w, c2b, ht_, nc);
        fc1_bt<<<15 * (nc / 512), 256, 0, stream>>>(
            ht_, f1w, f1b, a1t, nc);
        fc2_bt<<<12 * (nc / 512), 256, 0, stream>>>(
            a1t, f2w, f2b, a2t, nc);
        fc3_bt<<<8 * (nc / 512), 256, 0, stream>>>(
            a2t, f3w, f3b, embt, nc, N, n0);
    }
    proto_head_t<<<N / 256, 256, 0, stream>>>(embt, out, N);
}